// Round 3
// baseline (297.326 us; speedup 1.0000x reference)
//
#include <hip/hip_runtime.h>

#define HS   1024
#define SEQ  512
#define NBAT 64
#define INSZ 8
#define NM   4
#define DD   12

// DPP-based add: v += dpp_move(v). old=0, bound_ctrl=true.
#define DPP_ADD(v, ctrl, rmask, bmask) \
  v += __int_as_float(__builtin_amdgcn_update_dpp(0, __float_as_int(v), ctrl, rmask, bmask, true))

// Canonical gfx9 wave64 sum; lane 63 holds the 64-lane total afterwards.
__device__ __forceinline__ void wave64_sum2(float &a, float &b){
  DPP_ADD(a, 0x111, 0xf, 0xf); DPP_ADD(b, 0x111, 0xf, 0xf);  // row_shr:1
  DPP_ADD(a, 0x112, 0xf, 0xf); DPP_ADD(b, 0x112, 0xf, 0xf);  // row_shr:2
  DPP_ADD(a, 0x114, 0xf, 0xe); DPP_ADD(b, 0x114, 0xf, 0xe);  // row_shr:4
  DPP_ADD(a, 0x118, 0xf, 0xc); DPP_ADD(b, 0x118, 0xf, 0xc);  // row_shr:8
  DPP_ADD(a, 0x142, 0xa, 0xf); DPP_ADD(b, 0x142, 0xa, 0xf);  // row_bcast:15
  DPP_ADD(a, 0x143, 0xc, 0xf); DPP_ADD(b, 0x143, 0xc, 0xf);  // row_bcast:31
}

__global__ __launch_bounds__(256,1)
void rnn_scan(const float* __restrict__ x,
              const float* __restrict__ eps,
              const float* __restrict__ means,
              const float* __restrict__ tril,
              const float* __restrict__ mw,
              float* __restrict__ out)
{
  const int b    = blockIdx.x;
  const int tid  = threadIdx.x;
  const int wave = tid >> 6;
  const int lane = tid & 63;

  __shared__ __align__(16) float xs[SEQ*INSZ + 8];     // +pad for prefetch overrun
  __shared__ __align__(16) float outb[SEQ*10];         // staged outputs
  // Spin slots: red[parity][wave][r] = (float bits low32 | step-tag high32).
  // ds_*_b64 is a single DS access -> tag+data land/read atomically.
  __shared__ unsigned long long red[2][4][2];
  __shared__ float2 nsum[4];

  // ---- mixture weights ----
  float w[NM];
  {
    float s = 0.f;
    #pragma unroll
    for (int k=0;k<NM;k++){ w[k] = fmaxf(mw[k], 1e-6f); s += w[k]; }
    float inv = 1.0f/s;
    #pragma unroll
    for (int k=0;k<NM;k++) w[k] *= inv;
  }

  const float alpha = 0.1f;
  const float oma   = 0.9f;
  const float scl   = 500.0f/1024.0f;
  const float as2   = 2.0f*alpha*scl;   // h-state kept DOUBLED (g=2h): exp(g) direct
  const float a2    = 2.0f*alpha;

  // ---- preprocessing: mixed[i,0:12] for owned rows i = tid + j*256 ----
  float A0[4],A1[4],n0[4],n1[4],g[4];
  float2 Im2[4][4];                     // pre-scaled by 2*alpha
  #pragma unroll
  for (int j=0;j<4;j++){
    const int i = tid + j*256;
    float ep[NM][DD];
    #pragma unroll
    for (int k=0;k<NM;k++)
      #pragma unroll
      for (int d=0;d<DD;d++)
        ep[k][d] = eps[(k*HS + i)*DD + d];
    float mix[DD];
    #pragma unroll
    for (int e=0;e<DD;e++){
      float a = 0.f;
      #pragma unroll
      for (int k=0;k<NM;k++){
        float se = means[k*DD+e];
        for (int d=0; d<e; d++)
          se += ep[k][d]*tril[(k*DD+e)*DD + d];
        float dg = fabsf(tril[(k*DD+e)*DD + e] - 1e-12f) + 1e-12f;
        se += ep[k][e]*dg;
        a += w[k]*se;
      }
      mix[e] = a;
    }
    A0[j]=as2*mix[0]; A1[j]=as2*mix[1]; n0[j]=mix[2]; n1[j]=mix[3];
    #pragma unroll
    for (int e=0;e<4;e++) Im2[j][e]=make_float2(a2*mix[4+2*e], a2*mix[5+2*e]);
    g[j]=0.f;
  }

  // Nsum partials: u = Nsum - 2*sum(r*n) since tanh = 1 - 2r
  {
    float p0 = n0[0]+n0[1]+n0[2]+n0[3];
    float p1 = n1[0]+n1[1]+n1[2]+n1[3];
    wave64_sum2(p0,p1);
    if (lane==63) nsum[wave] = make_float2(p0,p1);
  }
  // init spin tags to impossible value
  if (tid < 16) ((unsigned long long*)red)[tid] = ~0ull;
  // stage x[b] into LDS (coalesced, one-time)
  for (int idx=tid; idx<SEQ*INSZ; idx+=256) xs[idx] = x[b*SEQ*INSZ + idx];
  __syncthreads();

  const float N0 = (nsum[0].x+nsum[1].x)+(nsum[2].x+nsum[3].x);
  const float N1 = (nsum[0].y+nsum[1].y)+(nsum[2].y+nsum[3].y);

  const float2* xs2 = (const float2*)xs;
  volatile unsigned long long (*vred)[4][2] =
      (volatile unsigned long long (*)[4][2])red;
  const int w4 = lane & 3;

  float o0=0.f, o1=0.f;
  float2 xt[4];
  #pragma unroll
  for (int e=0;e<4;e++) xt[e] = xs2[e];

  #pragma unroll 2
  for (int t=0;t<SEQ;t++){
    const int p = t&1;
    // wave partial: S_r = sum_own r_i * n_i,  r = rcp(exp(g)+1)
    float S0=0.f, S1=0.f;
    #pragma unroll
    for (int j=0;j<4;j++){
      float e = __expf(g[j]);
      float r = __builtin_amdgcn_rcpf(e + 1.0f);
      S0 = __builtin_fmaf(r, n0[j], S0);
      S1 = __builtin_fmaf(r, n1[j], S1);
    }
    wave64_sum2(S0,S1);
    {
      unsigned long long tagw = ((unsigned long long)(unsigned)t) << 32;
      unsigned long long q0 = tagw | __float_as_uint(S0);
      unsigned long long q1 = tagw | __float_as_uint(S1);
      if (lane==63){ vred[p][wave][0]=q0; vred[p][wave][1]=q1; }
    }

    // off-chain while partials propagate: inj from prefetched xt, next prefetch
    float inj[4];
    #pragma unroll
    for (int j=0;j<4;j++){
      float ax = __builtin_fmaf(xt[0].x, Im2[j][0].x, xt[1].x*Im2[j][1].x);
      float ay = __builtin_fmaf(xt[0].y, Im2[j][0].y, xt[1].y*Im2[j][1].y);
      ax = __builtin_fmaf(xt[2].x, Im2[j][2].x, ax);
      ay = __builtin_fmaf(xt[2].y, Im2[j][2].y, ay);
      ax = __builtin_fmaf(xt[3].x, Im2[j][3].x, ax);
      ay = __builtin_fmaf(xt[3].y, Im2[j][3].y, ay);
      inj[j] = ax + ay;
    }
    float2 xtn[4];
    #pragma unroll
    for (int e=0;e<4;e++) xtn[e] = xs2[(t+1)*4 + e];   // pad covers t=511

    // barrier-free rendezvous: poll wave (lane&3)'s slot until tag==t
    unsigned long long a, c;
    for (int spin=0; spin<(1<<20); ++spin){
      a = vred[p][w4][0];
      c = vred[p][w4][1];
      if (__all(((unsigned)(a>>32))==(unsigned)t &&
                ((unsigned)(c>>32))==(unsigned)t)) break;
    }
    float s0 = __uint_as_float((unsigned)a);
    float s1 = __uint_as_float((unsigned)c);
    // combine the 4 wave partials held across each quad: 2 quad_perm adds
    DPP_ADD(s0, 0xB1, 0xf, 0xf); DPP_ADD(s1, 0xB1, 0xf, 0xf);  // lane^1
    DPP_ADD(s0, 0x4E, 0xf, 0xf); DPP_ADD(s1, 0x4E, 0xf, 0xf);  // lane^2
    float U0 = __builtin_fmaf(-2.0f, s0, N0);
    float U1 = __builtin_fmaf(-2.0f, s1, N1);

    #pragma unroll
    for (int j=0;j<4;j++){
      float acc = __builtin_fmaf(A1[j], U1, inj[j]);
      acc = __builtin_fmaf(A0[j], U0, acc);
      g[j] = __builtin_fmaf(oma, g[j], acc);
    }

    if (tid==0){
      o0 = __builtin_fmaf(oma, o0, (alpha*scl)*U0);
      o1 = __builtin_fmaf(oma, o1, (alpha*scl)*U1);
      *(float2*)&outb[t*10] = make_float2(o0,o1);     // 40t bytes: 8B-aligned
    }
    #pragma unroll
    for (int e=0;e<4;e++) xt[e] = xtn[e];
  }

  // out[2..9] = EMA of x only -- independent of the scan; 8 threads, post-loop
  if (tid < 8){
    float o = 0.f;
    for (int t=0;t<SEQ;t++){
      o = __builtin_fmaf(oma, o, alpha*xs[t*8+tid]);
      outb[t*10+2+tid] = o;
    }
  }
  __syncthreads();

  // burst-dump staged outputs, coalesced float4
  const float4* ob4 = (const float4*)outb;
  float4* o4 = (float4*)out + b*(SEQ*10/4);
  for (int idx=tid; idx<SEQ*10/4; idx+=256) o4[idx] = ob4[idx];
}

extern "C" void kernel_launch(void* const* d_in, const int* in_sizes, int n_in,
                              void* d_out, int out_size, void* d_ws, size_t ws_size,
                              hipStream_t stream) {
  const float* x     = (const float*)d_in[0];  // (64,512,8)
  const float* eps   = (const float*)d_in[1];  // (4,1024,12)
  const float* means = (const float*)d_in[2];  // (4,12)
  const float* tril  = (const float*)d_in[3];  // (4,12,12)
  const float* mw    = (const float*)d_in[4];  // (4,)
  float* out = (float*)d_out;                  // (64,512,10) fp32

  rnn_scan<<<NBAT, 256, 0, stream>>>(x, eps, means, tril, mw, out);
}